// Round 11
// baseline (307.333 us; speedup 1.0000x reference)
//
#include <hip/hip_runtime.h>
#include <hip/hip_bf16.h>

#define D_IN 128
#define F 64          // H1 == H2 == D_OUT == 64
#define R_EDGES 2048  // edges per partition block (8 per thread, reg-staged)
#define NBIN 512      // dst-range sub-buckets

// ===================== ONE-PASS 512-bin partition, register-staged ==========
// Per 2048-edge block: each thread holds its 8 (src,dst,bin) triples in VGPRs.
// Phase 1: LDS count over 512 bins. Phase 2: one global atomic per nonempty bin
// (space reservation in final sub-bucket layout). Phase 3: scatter from regs.
// Edges are read from HBM exactly once; bins computed once.
__global__ __launch_bounds__(256) void part256_kernel(
        const int* __restrict__ src, const int* __restrict__ dst, int E,
        unsigned long long M37, int cap2,
        uint2* __restrict__ ebufA, int* __restrict__ bcur2) {
    __shared__ int cnt[NBIN], gb[NBIN];
    const int t = threadIdx.x;
    const int base = blockIdx.x * R_EDGES;

    for (int i = t; i < NBIN; i += 256) cnt[i] = 0;
    __syncthreads();

    int se[8], de[8], be[8];
#pragma unroll
    for (int it = 0; it < 8; ++it) {
        int i = base + it * 256 + t;
        be[it] = -1;
        if (i < E) {
            int d = dst[i];
            se[it] = src[i];
            de[it] = d;
            int b = (int)(((unsigned long long)(unsigned)d * M37) >> 37);
            be[it] = b;
            atomicAdd(&cnt[b], 1);
        }
    }
    __syncthreads();

    for (int i = t; i < NBIN; i += 256) {
        int c = cnt[i];
        gb[i] = (c > 0) ? atomicAdd(&bcur2[i], c) : 0;
        cnt[i] = 0;                    // reuse as block-local cursor
    }
    __syncthreads();

#pragma unroll
    for (int it = 0; it < 8; ++it) {
        if (be[it] >= 0) {
            int b = be[it];
            int p = atomicAdd(&cnt[b], 1);
            ebufA[(size_t)b * cap2 + gb[b] + p] =
                make_uint2((unsigned)se[it], (unsigned)de[it]);
        }
    }
}

// ===================== per-sub-bucket sort: counts, scan, csr, offsets, dinv ==========
// One block per sub-bucket (~196 nodes, ~3136 edges), 512 blocks = 2/CU.
// All per-edge atomics are LDS. Each block computes its own csr base by scanning
// bcur2[512] in-block (no separate scan kernel).
__global__ __launch_bounds__(256) void bsort_kernel(
        const uint2* __restrict__ ebufA, const int* __restrict__ bcur2,
        int cap2, int NPB, int n, int E,
        int* __restrict__ csr, int* __restrict__ offsets, float* __restrict__ dinv) {
    __shared__ int cnt[256], excl[256], bb[NBIN];
    const int sb = blockIdx.x, t = threadIdx.x;
    const int node0 = sb * NPB;
    const int nn = min(NPB, n - node0);

    // inline exclusive scan of bcur2[512] (8 chunks of 64, wave 0)
    for (int i = t; i < NBIN; i += 256) bb[i] = bcur2[i];
    __syncthreads();
    if (t < 64) {
        int carry = 0;
        for (int c4 = 0; c4 < NBIN / 64; ++c4) {
            int v = bb[c4 * 64 + t], x = v;
            for (int dlt = 1; dlt < 64; dlt <<= 1) { int y = __shfl_up(x, dlt); if (t >= dlt) x += y; }
            bb[c4 * 64 + t] = carry + x - v;     // exclusive
            carry += __shfl(x, 63);
        }
    }
    __syncthreads();

    if (sb == 0 && t == 0) offsets[n] = E;
    if (nn <= 0) return;
    const int cE = bcur2[sb];
    const int base = bb[sb];
    const uint2* eb = ebufA + (size_t)sb * cap2;

    cnt[t] = 0;
    __syncthreads();
    for (int i = t; i < cE; i += 256) atomicAdd(&cnt[eb[i].y - node0], 1);
    __syncthreads();

    if (t < 64) {                         // scan 256 = 4 chunks of 64, wave 0
        int carry = 0;
        for (int c4 = 0; c4 < 4; ++c4) {
            int v = cnt[c4 * 64 + t], x = v;
            for (int dlt = 1; dlt < 64; dlt <<= 1) { int y = __shfl_up(x, dlt); if (t >= dlt) x += y; }
            excl[c4 * 64 + t] = carry + x - v;
            carry += __shfl(x, 63);
        }
    }
    __syncthreads();

    if (t < nn) {
        offsets[node0 + t] = base + excl[t];
        dinv[node0 + t] = rsqrtf((float)cnt[t] + 1.0f);
    }
    __syncthreads();
    cnt[t] = excl[t];                     // cursors
    __syncthreads();
    for (int i = t; i < cE; i += 256) {
        uint2 e = eb[i];
        int p = atomicAdd(&cnt[e.y - node0], 1);
        csr[base + p] = (int)e.x;
    }
}

// ============ GEMM: h2[row] = dinv[row] * (relu?(A[row]) @ W), W is K x 64 ============
// k4 loop unroll CAPPED at 2: full unroll spilled to scratch (R2: 1.7GB traffic).
template<int K, bool RELU_IN>
__global__ __launch_bounds__(256) void gemm_kernel(
        const float* __restrict__ A, const float* __restrict__ W,
        const float* __restrict__ dinv, float* __restrict__ h2, int n) {
    constexpr int F4 = K / 4;
    __shared__ float4 Al[64 * F4];            // swizzled: phys k4 = k4 ^ ((r>>2) & 7)
    __shared__ float  Wl[K * F];
    const int t = threadIdx.x;

    for (int i = t; i < K * F / 4; i += 256)
        ((float4*)Wl)[i] = ((const float4*)W)[i];

    const int row0 = blockIdx.x * 64;
    for (int i = t; i < 64 * F4; i += 256) {
        int r = i / F4, k4 = i % F4;
        int gr = row0 + r; if (gr >= n) gr = n - 1;
        float4 v = ((const float4*)(A + (size_t)gr * K))[k4];
        if (RELU_IN) {
            v.x = fmaxf(v.x, 0.f); v.y = fmaxf(v.y, 0.f);
            v.z = fmaxf(v.z, 0.f); v.w = fmaxf(v.w, 0.f);
        }
        Al[r * F4 + (k4 ^ ((r >> 2) & 7))] = v;
    }
    __syncthreads();

    const int rg = t >> 4, cg = t & 15;
    const int r0 = rg * 4, c0 = cg * 4;
    const int sw = rg & 7;

    float acc[4][4] = {};
#pragma unroll 2
    for (int k4 = 0; k4 < F4; ++k4) {
        float4 a[4];
#pragma unroll
        for (int i = 0; i < 4; ++i) a[i] = Al[(r0 + i) * F4 + (k4 ^ sw)];
#pragma unroll
        for (int j = 0; j < 4; ++j) {
            float4 w = *(const float4*)&Wl[(k4 * 4 + j) * F + c0];
#pragma unroll
            for (int i = 0; i < 4; ++i) {
                float av = (j == 0) ? a[i].x : (j == 1) ? a[i].y : (j == 2) ? a[i].z : a[i].w;
                acc[i][0] = fmaf(av, w.x, acc[i][0]);
                acc[i][1] = fmaf(av, w.y, acc[i][1]);
                acc[i][2] = fmaf(av, w.z, acc[i][2]);
                acc[i][3] = fmaf(av, w.w, acc[i][3]);
            }
        }
    }

#pragma unroll
    for (int i = 0; i < 4; ++i) {
        int gr = row0 + r0 + i;
        if (gr < n) {
            float dv = dinv[gr];
            float4 o = make_float4(acc[i][0] * dv, acc[i][1] * dv,
                                   acc[i][2] * dv, acc[i][3] * dv);
            *(float4*)&h2[(size_t)gr * F + c0] = o;
        }
    }
}

// ============ aggregation: out[i] = b + dinv[i] * (h2[i] + sum_{s in in(i)} h2[s]) ============
// One wave per node. Lane = (edge-slot g in 0..7, feature-octet q8 in 0..7): each lane
// loads 2x float4 (32B) of its slot's row, 8 slots x 2-deep unroll = 16 row-gathers
// in flight per wave. Reduce across slots via shfl_xor(8,16,32).
// NOTE: flat at ~62us across R7/R9/R10 with FETCH at the 8-XCD compulsory floor
// (~190MB) -> at the random-gather fabric ceiling; do not touch.
__global__ __launch_bounds__(256) void agg_kernel(
        const int* __restrict__ offsets, const int* __restrict__ csr,
        const float* __restrict__ dinv, const float* __restrict__ h2,
        const float* __restrict__ bvec, float* __restrict__ out, int n) {
    const int wid  = (int)((blockIdx.x * 256u + threadIdx.x) >> 6);
    const int lane = threadIdx.x & 63;
    const int g = lane >> 3, q8 = lane & 7;
    if (wid >= n) return;
    const size_t fo = (size_t)q8 * 8;          // this lane's 32B chunk within the row

    const int beg = offsets[wid], end = offsets[wid + 1];

    float4 a00 = {0,0,0,0}, a01 = {0,0,0,0};   // leg 0 accumulator (8 floats)
    float4 a10 = {0,0,0,0}, a11 = {0,0,0,0};   // leg 1 accumulator
    if (g == 0) {
        a00 = *(const float4*)&h2[(size_t)wid * F + fo];
        a01 = *(const float4*)&h2[(size_t)wid * F + fo + 4];
    }

    int j = beg + g;
    for (; j + 8 < end; j += 16) {             // 16 rows in flight across the wave
        int s0 = csr[j], s1 = csr[j + 8];
        const float* r0 = &h2[(size_t)s0 * F + fo];
        const float* r1 = &h2[(size_t)s1 * F + fo];
        float4 v00 = *(const float4*)r0;
        float4 v01 = *(const float4*)(r0 + 4);
        float4 v10 = *(const float4*)r1;
        float4 v11 = *(const float4*)(r1 + 4);
        a00.x += v00.x; a00.y += v00.y; a00.z += v00.z; a00.w += v00.w;
        a01.x += v01.x; a01.y += v01.y; a01.z += v01.z; a01.w += v01.w;
        a10.x += v10.x; a10.y += v10.y; a10.z += v10.z; a10.w += v10.w;
        a11.x += v11.x; a11.y += v11.y; a11.z += v11.z; a11.w += v11.w;
    }
    if (j < end) {
        int s0 = csr[j];
        const float* r0 = &h2[(size_t)s0 * F + fo];
        float4 v00 = *(const float4*)r0;
        float4 v01 = *(const float4*)(r0 + 4);
        a00.x += v00.x; a00.y += v00.y; a00.z += v00.z; a00.w += v00.w;
        a01.x += v01.x; a01.y += v01.y; a01.z += v01.z; a01.w += v01.w;
    }
    a00.x += a10.x; a00.y += a10.y; a00.z += a10.z; a00.w += a10.w;
    a01.x += a11.x; a01.y += a11.y; a01.z += a11.z; a01.w += a11.w;

    // reduce across the 8 edge-slots
#pragma unroll
    for (int m = 8; m < 64; m <<= 1) {
        a00.x += __shfl_xor(a00.x, m); a00.y += __shfl_xor(a00.y, m);
        a00.z += __shfl_xor(a00.z, m); a00.w += __shfl_xor(a00.w, m);
        a01.x += __shfl_xor(a01.x, m); a01.y += __shfl_xor(a01.y, m);
        a01.z += __shfl_xor(a01.z, m); a01.w += __shfl_xor(a01.w, m);
    }

    if (g == 0) {
        float dv = dinv[wid];
        float4 b0 = *(const float4*)&bvec[fo];
        float4 b1 = *(const float4*)&bvec[fo + 4];
        float4 o0 = make_float4(fmaf(dv, a00.x, b0.x), fmaf(dv, a00.y, b0.y),
                                fmaf(dv, a00.z, b0.z), fmaf(dv, a00.w, b0.w));
        float4 o1 = make_float4(fmaf(dv, a01.x, b1.x), fmaf(dv, a01.y, b1.y),
                                fmaf(dv, a01.z, b1.z), fmaf(dv, a01.w, b1.w));
        *(float4*)&out[(size_t)wid * F + fo] = o0;
        *(float4*)&out[(size_t)wid * F + fo + 4] = o1;
    }
}

// ============ launch ============
extern "C" void kernel_launch(void* const* d_in, const int* in_sizes, int n_in,
                              void* d_out, int out_size, void* d_ws, size_t ws_size,
                              hipStream_t stream) {
    const float* x   = (const float*)d_in[0];
    const float* W1  = (const float*)d_in[1];
    const float* b1  = (const float*)d_in[2];
    const float* W2  = (const float*)d_in[3];
    const float* b2  = (const float*)d_in[4];
    const float* W3  = (const float*)d_in[5];
    const float* b3  = (const float*)d_in[6];
    const int*   ei  = (const int*)d_in[7];

    const int n = in_sizes[0] / D_IN;       // 100000
    const int E = in_sizes[7] / 2;          // 1600000
    const int* src = ei;
    const int* dst = ei + E;

    const int NPB = (n + NBIN - 1) / NBIN;                   // nodes per sub-bucket (196)
    const unsigned long long M37 = ((1ull << 37) / (unsigned long long)NPB) + 1;
    const int cap2 = 4096;                                   // sub-bucket capacity (+17 sigma)

    // ---- workspace layout ----
    char* p = (char*)d_ws;
    auto alloc = [&](size_t bytes) { char* q = p; p += (bytes + 255) & ~(size_t)255; return q; };
    int*   bcur2   = (int*)  alloc(NBIN * 4);
    int*   offsets = (int*)  alloc((size_t)(n + 1) * 4);
    float* dinv    = (float*)alloc((size_t)n * 4);
    int*   csr     = (int*)  alloc((size_t)E * 4);
    float* h2      = (float*)alloc((size_t)n * F * 4);       // 25.6 MB
    float* outA    = (float*)alloc((size_t)n * F * 4);       // 25.6 MB
    float* outF    = (float*)d_out;

    // edge buffer aliases the (not-yet-live) outA region: ebufA dies after bsort,
    // outA first written by agg1.
    uint2* ebufA = (uint2*)outA;  // 512 * 4096 * 8B = 16.8 MB <= 25.6 MB

    const int pBlocks = (E + R_EDGES - 1) / R_EDGES;         // 782
    const int gBlocks = (n + 63) / 64;
    const int aBlocks = (int)(((size_t)n * 64 + 255) / 256);

    // ---- CSR build (also produces dinv) ----
    hipMemsetAsync(bcur2, 0, NBIN * 4, stream);
    part256_kernel<<<pBlocks, 256, 0, stream>>>(src, dst, E, M37, cap2, ebufA, bcur2);
    bsort_kernel  <<<NBIN,    256, 0, stream>>>(ebufA, bcur2, cap2, NPB, n, E,
                                                csr, offsets, dinv);

    // ---- layer 1: x (K=128) ----
    gemm_kernel<D_IN, false><<<gBlocks, 256, 0, stream>>>(x, W1, dinv, h2, n);
    agg_kernel<<<aBlocks, 256, 0, stream>>>(offsets, csr, dinv, h2, b1, outA, n);

    // ---- layer 2: relu(outA) (K=64) ----
    gemm_kernel<F, true><<<gBlocks, 256, 0, stream>>>(outA, W2, dinv, h2, n);
    agg_kernel<<<aBlocks, 256, 0, stream>>>(offsets, csr, dinv, h2, b2, outA, n);

    // ---- layer 3: relu(outA) (K=64) ----
    gemm_kernel<F, true><<<gBlocks, 256, 0, stream>>>(outA, W3, dinv, h2, n);
    agg_kernel<<<aBlocks, 256, 0, stream>>>(offsets, csr, dinv, h2, b3, outF, n);
}